// Round 1
// baseline (45271.198 us; speedup 1.0000x reference)
//
#include <hip/hip_runtime.h>
#include <stdint.h>

#define B_    16
#define N_    65536
#define NPTS  (B_*N_)
#define NBK   11
#define NFEAT 259

// ---- workspace float offsets ----
enum {
  OFF_S1SUM = 0,      // 64
  OFF_S1SQ  = 64,     // 64
  OFF_YMINU = 128,    // 16 (uint keys)
  OFF_YMAXU = 144,    // 16
  OFF_YMINF = 160,    // 16
  OFF_YMAXF = 176,    // 16
  OFF_A1    = 192,    // 64
  OFF_C1    = 256,    // 64
  OFF_S2SUM = 320,    // 128
  OFF_S2SQ  = 448,    // 128
  OFF_A2    = 576,    // 128
  OFF_C2    = 704,    // 128
  OFF_SX    = 832,    // 176
  OFF_SZ    = 1008,   // 176
  OFF_CNT   = 1184,   // 176
  OFF_CX    = 1360,   // 176
  OFF_CZ    = 1536,   // 176
  OFF_S3SUM = 1712,   // 256
  OFF_S3SQ  = 1968,   // 256
  OFF_A3    = 2224,   // 256
  OFF_C3    = 2480,   // 256
  OFF_FMAXU = 2736,   // 16*259 (uint keys)
  OFF_FSUM  = 6880,   // 16*259
  OFF_END   = 11024
};
#define H3_BYTE_OFF  (64*1024)
#define TIER1_BYTES  ((size_t)H3_BYTE_OFF + (size_t)NPTS*256*2)

// ---- helpers ----
__device__ __forceinline__ float wave_sum(float v){
  #pragma unroll
  for (int m=32;m>=1;m>>=1) v += __shfl_xor(v,m,64);
  return v;
}
__device__ __forceinline__ float wave_max(float v){
  #pragma unroll
  for (int m=32;m>=1;m>>=1) v = fmaxf(v,__shfl_xor(v,m,64));
  return v;
}
__device__ __forceinline__ float wave_min(float v){
  #pragma unroll
  for (int m=32;m>=1;m>>=1) v = fminf(v,__shfl_xor(v,m,64));
  return v;
}
// monotonic uint key for float atomic min/max
__device__ __forceinline__ unsigned fkey(float f){
  unsigned u=__float_as_uint(f);
  return (u & 0x80000000u) ? ~u : (u | 0x80000000u);
}
__device__ __forceinline__ float funkey(unsigned u){
  return __uint_as_float((u & 0x80000000u) ? (u ^ 0x80000000u) : ~u);
}
__device__ __forceinline__ unsigned short bf16_bits(float f){
  unsigned u=__float_as_uint(f);
  u += 0x7FFFu + ((u>>16)&1u);
  return (unsigned short)(u>>16);
}
__device__ __forceinline__ float bfu(unsigned short s){
  return __uint_as_float(((unsigned)s)<<16);
}

// ---- init ----
__global__ void k_init(float* __restrict__ ws){
  int t=threadIdx.x;
  for (int i=t;i<OFF_END;i+=256) ws[i]=0.f;
  __syncthreads();
  unsigned* wsu=(unsigned*)ws;
  if (t<16) wsu[OFF_YMINU+t]=0xFFFFFFFFu;   // key for +inf
}

// ---- pass A: h1 stats + per-batch y min/max ----
__global__ __launch_bounds__(256,2) void k_passA(
    const float* __restrict__ x,
    const float* __restrict__ w1, const float* __restrict__ b1,
    float* __restrict__ ws)
{
  __shared__ float slots[4][64][2];
  const int t=threadIdx.x, lane=t&63, wid=t>>6;
  const int bid=blockIdx.x, b=bid>>5, chunk=bid&31;
  float* sp=&slots[0][0][0];
  for (int i=t;i<4*64*2;i+=256) sp[i]=0.f;
  __syncthreads();
  const int base=b*N_+chunk*2048+wid*512;
  float ymn=3.4e38f, ymx=-3.4e38f;
  #pragma unroll 1
  for (int it=0; it<8; ++it){
    const int p=base+it*64+lane;
    const float x0=x[p*3+0], x1=x[p*3+1], x2=x[p*3+2];
    ymn=fminf(ymn,x1); ymx=fmaxf(ymx,x1);
    #pragma unroll
    for (int jb=0;jb<4;jb++){
      float acc[16];
      #pragma unroll
      for (int jj=0;jj<16;jj++){
        const int j=jb*16+jj;
        float h=b1[j];
        h=fmaf(x0,w1[j],h); h=fmaf(x1,w1[64+j],h); h=fmaf(x2,w1[128+j],h);
        acc[jj]=h;
      }
      #pragma unroll
      for (int jj=0;jj<16;jj++){
        const float s=wave_sum(acc[jj]);
        const float q=wave_sum(acc[jj]*acc[jj]);
        if (lane==0){ slots[wid][jb*16+jj][0]+=s; slots[wid][jb*16+jj][1]+=q; }
      }
    }
  }
  ymn=wave_min(ymn); ymx=wave_max(ymx);
  if (lane==0){
    atomicMin((unsigned*)ws+OFF_YMINU+b, fkey(ymn));
    atomicMax((unsigned*)ws+OFF_YMAXU+b, fkey(ymx));
  }
  __syncthreads();
  for (int j=t;j<64;j+=256){
    float s=slots[0][j][0]+slots[1][j][0]+slots[2][j][0]+slots[3][j][0];
    float q=slots[0][j][1]+slots[1][j][1]+slots[2][j][1]+slots[3][j][1];
    atomicAdd(&ws[OFF_S1SUM+j],s);
    atomicAdd(&ws[OFF_S1SQ +j],q);
  }
}

__global__ void k_finA(const float* __restrict__ gm, const float* __restrict__ bt,
                       float* __restrict__ ws){
  int t=threadIdx.x;
  if (t<64){
    const float inv=1.f/(float)NPTS;
    float m=ws[OFF_S1SUM+t]*inv;
    float v=ws[OFF_S1SQ+t]*inv - m*m;
    float r=1.f/sqrtf(v+1e-5f);
    float a=gm[t]*r;
    ws[OFF_A1+t]=a; ws[OFF_C1+t]=bt[t]-m*a;
  }
  if (t<16){
    unsigned* wsu=(unsigned*)ws;
    ws[OFF_YMINF+t]=funkey(wsu[OFF_YMINU+t]);
    ws[OFF_YMAXF+t]=funkey(wsu[OFF_YMAXU+t]);
  }
}

// ---- pass B: bucket segment sums + h2 stats ----
__global__ __launch_bounds__(256,2) void k_passB(
    const float* __restrict__ x,
    const float* __restrict__ w1, const float* __restrict__ b1,
    const float* __restrict__ w2, const float* __restrict__ b2,
    float* __restrict__ ws)
{
  __shared__ unsigned short g1t[4][64][64];
  __shared__ float slots[4][128][2];
  const int t=threadIdx.x, lane=t&63, wid=t>>6;
  const int bid=blockIdx.x, b=bid>>5, chunk=bid&31;
  float* sp=&slots[0][0][0];
  for (int i=t;i<4*128*2;i+=256) sp[i]=0.f;
  __syncthreads();
  const float ymn=ws[OFF_YMINF+b], ymx=ws[OFF_YMAXF+b];
  const float* a1=ws+OFF_A1; const float* c1=ws+OFF_C1;
  float sxl[NBK], szl[NBK], cntl[NBK];
  #pragma unroll
  for (int k=0;k<NBK;k++){ sxl[k]=0.f; szl[k]=0.f; cntl[k]=0.f; }
  const int base=b*N_+chunk*2048+wid*512;
  #pragma unroll 1
  for (int it=0; it<8; ++it){
    const int p=base+it*64+lane;
    const float x0=x[p*3+0], x1=x[p*3+1], x2=x[p*3+2];
    // bucket accumulation (match reference: trunc((y-min)/(max-min+1e-6)*10), clip 0..10)
    const float yn=(x1-ymn)/(ymx-ymn+1e-6f);
    int bk=(int)(yn*10.f); bk = bk<0?0:(bk>10?10:bk);
    #pragma unroll
    for (int k=0;k<NBK;k++){
      const bool m=(bk==k);
      sxl[k]+= m?x0:0.f; szl[k]+= m?x2:0.f; cntl[k]+= m?1.f:0.f;
    }
    // g1 -> per-lane LDS column (bf16)
    #pragma unroll
    for (int jb=0;jb<4;jb++){
      #pragma unroll
      for (int jj=0;jj<16;jj++){
        const int j=jb*16+jj;
        float h=b1[j];
        h=fmaf(x0,w1[j],h); h=fmaf(x1,w1[64+j],h); h=fmaf(x2,w1[128+j],h);
        const float g=fmaxf(0.f, fmaf(h,a1[j],c1[j]));
        g1t[wid][j][lane]=bf16_bits(g);
      }
    }
    // h2 stats
    #pragma unroll 1
    for (int jb=0;jb<8;jb++){
      float acc[16];
      #pragma unroll
      for (int jj=0;jj<16;jj++) acc[jj]=b2[jb*16+jj];
      #pragma unroll 4
      for (int k=0;k<64;k++){
        const float g=bfu(g1t[wid][k][lane]);
        #pragma unroll
        for (int jj=0;jj<16;jj++) acc[jj]=fmaf(g,w2[k*128+jb*16+jj],acc[jj]);
      }
      #pragma unroll
      for (int jj=0;jj<16;jj++){
        const float h=acc[jj];
        const float s=wave_sum(h);
        const float q=wave_sum(h*h);
        if (lane==0){ slots[wid][jb*16+jj][0]+=s; slots[wid][jb*16+jj][1]+=q; }
      }
    }
  }
  // flush buckets
  #pragma unroll
  for (int k=0;k<NBK;k++){
    const float s=wave_sum(sxl[k]);
    const float z=wave_sum(szl[k]);
    const float c=wave_sum(cntl[k]);
    if (lane==0){
      atomicAdd(&ws[OFF_SX +b*NBK+k],s);
      atomicAdd(&ws[OFF_SZ +b*NBK+k],z);
      atomicAdd(&ws[OFF_CNT+b*NBK+k],c);
    }
  }
  __syncthreads();
  for (int j=t;j<128;j+=256){
    float s=slots[0][j][0]+slots[1][j][0]+slots[2][j][0]+slots[3][j][0];
    float q=slots[0][j][1]+slots[1][j][1]+slots[2][j][1]+slots[3][j][1];
    atomicAdd(&ws[OFF_S2SUM+j],s);
    atomicAdd(&ws[OFF_S2SQ +j],q);
  }
}

__global__ void k_finB(const float* __restrict__ gm, const float* __restrict__ bt,
                       float* __restrict__ ws){
  int t=threadIdx.x;
  if (t<128){
    const float inv=1.f/(float)NPTS;
    float m=ws[OFF_S2SUM+t]*inv;
    float v=ws[OFF_S2SQ+t]*inv - m*m;
    float r=1.f/sqrtf(v+1e-5f);
    float a=gm[t]*r;
    ws[OFF_A2+t]=a; ws[OFF_C2+t]=bt[t]-m*a;
  }
  if (t<176){
    const float c=ws[OFF_CNT+t];
    const float d=fmaxf(c,1.f);
    ws[OFF_CX+t]=ws[OFF_SX+t]/d;
    ws[OFF_CZ+t]=ws[OFF_SZ+t]/d;
  }
}

// ---- pass C: h3 stats (+optional bf16 spill) ----
template<int STORE>
__global__ __launch_bounds__(256,2) void k_passC(
    const float* __restrict__ x,
    const float* __restrict__ w1, const float* __restrict__ b1,
    const float* __restrict__ w2, const float* __restrict__ b2,
    const float* __restrict__ w3, const float* __restrict__ b3,
    float* __restrict__ ws, unsigned short* __restrict__ h3buf)
{
  __shared__ unsigned short g1t[4][64][64];
  __shared__ float slots[4][256][2];
  const int t=threadIdx.x, lane=t&63, wid=t>>6;
  const int bid=blockIdx.x, b=bid>>5, chunk=bid&31;
  float* sp=&slots[0][0][0];
  for (int i=t;i<4*256*2;i+=256) sp[i]=0.f;
  __syncthreads();
  const float* a1=ws+OFF_A1; const float* c1=ws+OFF_C1;
  const float* a2=ws+OFF_A2; const float* c2=ws+OFF_C2;
  const int base=b*N_+chunk*2048+wid*512;
  #pragma unroll 1
  for (int it=0; it<8; ++it){
    const int p=base+it*64+lane;
    const float x0=x[p*3+0], x1=x[p*3+1], x2=x[p*3+2];
    #pragma unroll
    for (int jb=0;jb<4;jb++){
      #pragma unroll
      for (int jj=0;jj<16;jj++){
        const int j=jb*16+jj;
        float h=b1[j];
        h=fmaf(x0,w1[j],h); h=fmaf(x1,w1[64+j],h); h=fmaf(x2,w1[128+j],h);
        const float g=fmaxf(0.f, fmaf(h,a1[j],c1[j]));
        g1t[wid][j][lane]=bf16_bits(g);
      }
    }
    // g2 in registers (all static indexing)
    float g2r[128];
    #pragma unroll
    for (int jb=0;jb<8;jb++){
      float acc[16];
      #pragma unroll
      for (int jj=0;jj<16;jj++) acc[jj]=b2[jb*16+jj];
      #pragma unroll 4
      for (int k=0;k<64;k++){
        const float g=bfu(g1t[wid][k][lane]);
        #pragma unroll
        for (int jj=0;jj<16;jj++) acc[jj]=fmaf(g,w2[k*128+jb*16+jj],acc[jj]);
      }
      #pragma unroll
      for (int jj=0;jj<16;jj++)
        g2r[jb*16+jj]=fmaxf(0.f, fmaf(acc[jj],a2[jb*16+jj],c2[jb*16+jj]));
    }
    // h3 = g2 @ w3 + b3 ; accumulate stats
    #pragma unroll 1
    for (int jb=0;jb<16;jb++){
      float acc[16];
      #pragma unroll
      for (int jj=0;jj<16;jj++) acc[jj]=b3[jb*16+jj];
      #pragma unroll
      for (int k=0;k<128;k++){
        const float g=g2r[k];
        #pragma unroll
        for (int jj=0;jj<16;jj++) acc[jj]=fmaf(g,w3[k*256+jb*16+jj],acc[jj]);
      }
      #pragma unroll
      for (int jj=0;jj<16;jj++){
        const float h=acc[jj];
        if (STORE) h3buf[(size_t)(jb*16+jj)*NPTS + p]=bf16_bits(h);
        const float s=wave_sum(h);
        const float q=wave_sum(h*h);
        if (lane==0){ slots[wid][jb*16+jj][0]+=s; slots[wid][jb*16+jj][1]+=q; }
      }
    }
  }
  __syncthreads();
  for (int j=t;j<256;j+=256){
    float s=slots[0][j][0]+slots[1][j][0]+slots[2][j][0]+slots[3][j][0];
    float q=slots[0][j][1]+slots[1][j][1]+slots[2][j][1]+slots[3][j][1];
    atomicAdd(&ws[OFF_S3SUM+j],s);
    atomicAdd(&ws[OFF_S3SQ +j],q);
  }
}

__global__ void k_finC(const float* __restrict__ gm, const float* __restrict__ bt,
                       float* __restrict__ ws){
  int t=threadIdx.x;
  if (t<256){
    const float inv=1.f/(float)NPTS;
    float m=ws[OFF_S3SUM+t]*inv;
    float v=ws[OFF_S3SQ+t]*inv - m*m;
    float r=1.f/sqrtf(v+1e-5f);
    float a=gm[t]*r;
    ws[OFF_A3+t]=a; ws[OFF_C3+t]=bt[t]-m*a;
  }
}

// spatial features + reduce into slots (shared by both pass-D variants)
__device__ __forceinline__ void spatial_reduce(
    float x0,float x1,float x2, int b, const float* __restrict__ ws,
    float ymn,float ymx, int lane,int wid, float slots[4][NFEAT][2])
{
  const float yn=(x1-ymn)/(ymx-ymn+1e-6f);
  int bk=(int)(yn*10.f); bk = bk<0?0:(bk>10?10:bk);
  const float cxv=ws[OFF_CX+b*NBK+bk];
  const float czv=ws[OFF_CZ+b*NBK+bk];
  const float dx=x0-cxv, dz=x2-czv;
  const float r=sqrtf(fmaf(dx,dx,dz*dz));
  const float sn=(r>0.f)?(dz/r):0.f;
  const float cs=(r>0.f)?(dx/r):1.f;
  float v[3]={sn,cs,r};
  #pragma unroll
  for (int q=0;q<3;q++){
    const float mx=wave_max(v[q]);
    const float s =wave_sum(v[q]);
    if (lane==0){
      slots[wid][256+q][0]=fmaxf(slots[wid][256+q][0],mx);
      slots[wid][256+q][1]+=s;
    }
  }
}

__device__ __forceinline__ void flush_feat(
    int t,int b, float slots[4][NFEAT][2], float* __restrict__ ws)
{
  __syncthreads();
  for (int j=t;j<NFEAT;j+=256){
    float mx=fmaxf(fmaxf(slots[0][j][0],slots[1][j][0]),
                   fmaxf(slots[2][j][0],slots[3][j][0]));
    float s = slots[0][j][1]+slots[1][j][1]+slots[2][j][1]+slots[3][j][1];
    atomicMax((unsigned*)ws+OFF_FMAXU+b*NFEAT+j, fkey(mx));
    atomicAdd(&ws[OFF_FSUM+b*NFEAT+j], s);
  }
}

// ---- pass D (tier0): full recompute + pool ----
__global__ __launch_bounds__(256,2) void k_passD_full(
    const float* __restrict__ x,
    const float* __restrict__ w1, const float* __restrict__ b1,
    const float* __restrict__ w2, const float* __restrict__ b2,
    const float* __restrict__ w3, const float* __restrict__ b3,
    float* __restrict__ ws)
{
  __shared__ unsigned short g1t[4][64][64];
  __shared__ float slots[4][NFEAT][2];
  const int t=threadIdx.x, lane=t&63, wid=t>>6;
  const int bid=blockIdx.x, b=bid>>5, chunk=bid&31;
  float* sp=&slots[0][0][0];
  for (int i=t;i<4*NFEAT*2;i+=256) sp[i]=(i&1)?0.f:-3.4e38f;
  __syncthreads();
  const float ymn=ws[OFF_YMINF+b], ymx=ws[OFF_YMAXF+b];
  const float* a1=ws+OFF_A1; const float* c1=ws+OFF_C1;
  const float* a2=ws+OFF_A2; const float* c2=ws+OFF_C2;
  const float* a3=ws+OFF_A3; const float* c3=ws+OFF_C3;
  const int base=b*N_+chunk*2048+wid*512;
  #pragma unroll 1
  for (int it=0; it<8; ++it){
    const int p=base+it*64+lane;
    const float x0=x[p*3+0], x1=x[p*3+1], x2=x[p*3+2];
    spatial_reduce(x0,x1,x2,b,ws,ymn,ymx,lane,wid,slots);
    #pragma unroll
    for (int jb=0;jb<4;jb++){
      #pragma unroll
      for (int jj=0;jj<16;jj++){
        const int j=jb*16+jj;
        float h=b1[j];
        h=fmaf(x0,w1[j],h); h=fmaf(x1,w1[64+j],h); h=fmaf(x2,w1[128+j],h);
        const float g=fmaxf(0.f, fmaf(h,a1[j],c1[j]));
        g1t[wid][j][lane]=bf16_bits(g);
      }
    }
    float g2r[128];
    #pragma unroll
    for (int jb=0;jb<8;jb++){
      float acc[16];
      #pragma unroll
      for (int jj=0;jj<16;jj++) acc[jj]=b2[jb*16+jj];
      #pragma unroll 4
      for (int k=0;k<64;k++){
        const float g=bfu(g1t[wid][k][lane]);
        #pragma unroll
        for (int jj=0;jj<16;jj++) acc[jj]=fmaf(g,w2[k*128+jb*16+jj],acc[jj]);
      }
      #pragma unroll
      for (int jj=0;jj<16;jj++)
        g2r[jb*16+jj]=fmaxf(0.f, fmaf(acc[jj],a2[jb*16+jj],c2[jb*16+jj]));
    }
    #pragma unroll 1
    for (int jb=0;jb<16;jb++){
      float acc[16];
      #pragma unroll
      for (int jj=0;jj<16;jj++) acc[jj]=b3[jb*16+jj];
      #pragma unroll
      for (int k=0;k<128;k++){
        const float g=g2r[k];
        #pragma unroll
        for (int jj=0;jj<16;jj++) acc[jj]=fmaf(g,w3[k*256+jb*16+jj],acc[jj]);
      }
      #pragma unroll
      for (int jj=0;jj<16;jj++){
        const int j=jb*16+jj;
        const float g=fmaxf(0.f, fmaf(acc[jj],a3[j],c3[j]));
        const float mx=wave_max(g);
        const float s =wave_sum(g);
        if (lane==0){ slots[wid][j][0]=fmaxf(slots[wid][j][0],mx); slots[wid][j][1]+=s; }
      }
    }
  }
  flush_feat(t,b,slots,ws);
}

// ---- pass D (tier1): stream spilled h3, j-chunked deferred reduction ----
__global__ __launch_bounds__(256,2) void k_passD_light(
    const float* __restrict__ x,
    const unsigned short* __restrict__ h3buf,
    float* __restrict__ ws)
{
  __shared__ float slots[4][NFEAT][2];
  const int t=threadIdx.x, lane=t&63, wid=t>>6;
  const int bid=blockIdx.x, b=bid>>5, chunk=bid&31;
  float* sp=&slots[0][0][0];
  for (int i=t;i<4*NFEAT*2;i+=256) sp[i]=(i&1)?0.f:-3.4e38f;
  __syncthreads();
  const float ymn=ws[OFF_YMINF+b], ymx=ws[OFF_YMAXF+b];
  const float* a3=ws+OFF_A3; const float* c3=ws+OFF_C3;
  const int base=b*N_+chunk*2048+wid*512;
  #pragma unroll 1
  for (int it=0; it<8; ++it){
    const int p=base+it*64+lane;
    const float x0=x[p*3+0], x1=x[p*3+1], x2=x[p*3+2];
    spatial_reduce(x0,x1,x2,b,ws,ymn,ymx,lane,wid,slots);
  }
  #pragma unroll 1
  for (int jc=0;jc<8;jc++){
    float a3r[32], c3r[32], amx[32], asum[32];
    #pragma unroll
    for (int jj=0;jj<32;jj++){
      a3r[jj]=a3[jc*32+jj]; c3r[jj]=c3[jc*32+jj];
      amx[jj]=-3.4e38f; asum[jj]=0.f;
    }
    #pragma unroll 1
    for (int it=0; it<8; ++it){
      const int p=base+it*64+lane;
      #pragma unroll
      for (int jj=0;jj<32;jj++){
        const int j=jc*32+jj;
        const float h=bfu(h3buf[(size_t)j*NPTS+p]);
        const float g=fmaxf(0.f, fmaf(h,a3r[jj],c3r[jj]));
        amx[jj]=fmaxf(amx[jj],g);
        asum[jj]+=g;
      }
    }
    #pragma unroll
    for (int jj=0;jj<32;jj++){
      const float mx=wave_max(amx[jj]);
      const float s =wave_sum(asum[jj]);
      if (lane==0){
        const int j=jc*32+jj;
        slots[wid][j][0]=fmaxf(slots[wid][j][0],mx);
        slots[wid][j][1]+=s;
      }
    }
  }
  flush_feat(t,b,slots,ws);
}

// ---- final: feat_cat @ wp + bp, LayerNorm ----
__global__ __launch_bounds__(256) void k_final(
    const float* __restrict__ wp, const float* __restrict__ bp,
    const float* __restrict__ gln, const float* __restrict__ bln,
    float* __restrict__ out, const float* __restrict__ ws)
{
  __shared__ float feat[518];
  __shared__ float red[256];
  const int b=blockIdx.x, t=threadIdx.x;
  const unsigned* wsu=(const unsigned*)ws;
  for (int i=t;i<NFEAT;i+=256){
    feat[i]       = funkey(wsu[OFF_FMAXU+b*NFEAT+i]);
    feat[NFEAT+i] = ws[OFF_FSUM+b*NFEAT+i]*(1.f/65536.f);
  }
  __syncthreads();
  float o0=bp[t], o1=bp[t+256];
  #pragma unroll 4
  for (int i=0;i<518;i++){
    const float f=feat[i];
    o0=fmaf(f, wp[i*512+t],     o0);
    o1=fmaf(f, wp[i*512+t+256], o1);
  }
  red[t]=o0+o1; __syncthreads();
  for (int s=128;s>0;s>>=1){ if (t<s) red[t]+=red[t+s]; __syncthreads(); }
  const float mu=red[0]*(1.f/512.f);
  __syncthreads();
  const float d0=o0-mu, d1=o1-mu;
  red[t]=d0*d0+d1*d1; __syncthreads();
  for (int s=128;s>0;s>>=1){ if (t<s) red[t]+=red[t+s]; __syncthreads(); }
  const float var=red[0]*(1.f/512.f);
  const float rs=1.f/sqrtf(var+1e-5f);
  out[b*512+t]     = d0*rs*gln[t]    +bln[t];
  out[b*512+t+256] = d1*rs*gln[t+256]+bln[t+256];
}

extern "C" void kernel_launch(void* const* d_in, const int* in_sizes, int n_in,
                              void* d_out, int out_size, void* d_ws, size_t ws_size,
                              hipStream_t stream)
{
  const float* x  =(const float*)d_in[0];
  const float* w1 =(const float*)d_in[1];
  const float* b1 =(const float*)d_in[2];
  const float* gm1=(const float*)d_in[3];
  const float* be1=(const float*)d_in[4];
  const float* w2 =(const float*)d_in[5];
  const float* b2 =(const float*)d_in[6];
  const float* gm2=(const float*)d_in[7];
  const float* be2=(const float*)d_in[8];
  const float* w3 =(const float*)d_in[9];
  const float* b3 =(const float*)d_in[10];
  const float* gm3=(const float*)d_in[11];
  const float* be3=(const float*)d_in[12];
  const float* wp =(const float*)d_in[13];
  const float* bp =(const float*)d_in[14];
  const float* gln=(const float*)d_in[15];
  const float* bln=(const float*)d_in[16];
  float* ws=(float*)d_ws;
  float* out=(float*)d_out;
  unsigned short* h3buf=(unsigned short*)((char*)d_ws + H3_BYTE_OFF);
  const bool tier1 = (ws_size >= TIER1_BYTES);

  k_init<<<dim3(1),dim3(256),0,stream>>>(ws);
  k_passA<<<dim3(512),dim3(256),0,stream>>>(x,w1,b1,ws);
  k_finA<<<dim3(1),dim3(256),0,stream>>>(gm1,be1,ws);
  k_passB<<<dim3(512),dim3(256),0,stream>>>(x,w1,b1,w2,b2,ws);
  k_finB<<<dim3(1),dim3(256),0,stream>>>(gm2,be2,ws);
  if (tier1)
    k_passC<1><<<dim3(512),dim3(256),0,stream>>>(x,w1,b1,w2,b2,w3,b3,ws,h3buf);
  else
    k_passC<0><<<dim3(512),dim3(256),0,stream>>>(x,w1,b1,w2,b2,w3,b3,ws,h3buf);
  k_finC<<<dim3(1),dim3(256),0,stream>>>(gm3,be3,ws);
  if (tier1)
    k_passD_light<<<dim3(512),dim3(256),0,stream>>>(x,h3buf,ws);
  else
    k_passD_full<<<dim3(512),dim3(256),0,stream>>>(x,w1,b1,w2,b2,w3,b3,ws);
  k_final<<<dim3(16),dim3(256),0,stream>>>(wp,bp,gln,bln,out,ws);
}

// Round 2
// 700.904 us; speedup vs baseline: 64.5897x; 64.5897x over previous
//
#include <hip/hip_runtime.h>
#include <stdint.h>

#define B_    16
#define N_    65536
#define NPTS  (B_*N_)
#define NBK   11
#define NFEAT 259
#define NF    ((float)NPTS)

typedef float f32x4 __attribute__((ext_vector_type(4)));
typedef short s16x8 __attribute__((ext_vector_type(8)));

// ---- workspace float offsets ----
enum {
  OFF_SXV   = 0,     // 3  (sum x0,x1,x2 over all points)
  OFF_SXX   = 4,     // 6  (xx: 00,01,02,11,12,22)
  OFF_YMINU = 16,    // 16 (uint keys)
  OFF_YMAXU = 32,    // 16
  OFF_YMINF = 48,    // 16
  OFF_YMAXF = 64,    // 16
  OFF_A1    = 80,    // 64
  OFF_C1    = 144,   // 64
  OFF_S2SUM = 208,   // 128
  OFF_S2SQ  = 336,   // 128
  OFF_A2    = 464,   // 128
  OFF_C2    = 592,   // 128
  OFF_SX    = 720,   // 176
  OFF_SZ    = 896,   // 176
  OFF_CNT   = 1072,  // 176
  OFF_CX    = 1248,  // 176
  OFF_CZ    = 1424,  // 176
  OFF_S3SUM = 1600,  // 256
  OFF_S3SQ  = 1856,  // 256
  OFF_A3    = 2112,  // 256
  OFF_C3    = 2368,  // 256
  OFF_FMAXU = 2624,  // 16*259 uint keys
  OFF_FSUM  = 6768,  // 16*259
  OFF_END   = 10912
};

// ---- helpers ----
__device__ __forceinline__ float wave_sum(float v){
  #pragma unroll
  for (int m=32;m>=1;m>>=1) v += __shfl_xor(v,m,64);
  return v;
}
__device__ __forceinline__ float wave_max(float v){
  #pragma unroll
  for (int m=32;m>=1;m>>=1) v = fmaxf(v,__shfl_xor(v,m,64));
  return v;
}
__device__ __forceinline__ float wave_min(float v){
  #pragma unroll
  for (int m=32;m>=1;m>>=1) v = fminf(v,__shfl_xor(v,m,64));
  return v;
}
__device__ __forceinline__ unsigned fkey(float f){
  unsigned u=__float_as_uint(f);
  return (u & 0x80000000u) ? ~u : (u | 0x80000000u);
}
__device__ __forceinline__ float funkey(unsigned u){
  return __uint_as_float((u & 0x80000000u) ? (u ^ 0x80000000u) : ~u);
}
__device__ __forceinline__ unsigned short bf16_bits(float f){
  unsigned u=__float_as_uint(f);
  u += 0x7FFFu + ((u>>16)&1u);
  return (unsigned short)(u>>16);
}

// ---- init ----
__global__ void k_init(float* __restrict__ ws){
  int t=threadIdx.x;
  for (int i=t;i<OFF_END;i+=256) ws[i]=0.f;
  __syncthreads();
  unsigned* wsu=(unsigned*)ws;
  if (t<16) wsu[OFF_YMINU+t]=0xFFFFFFFFu;
}

// ---- pass A: x colsums + X^T X + per-batch y min/max (pure stream) ----
__global__ __launch_bounds__(256) void k_stream0(const float* __restrict__ x,
                                                 float* __restrict__ ws){
  const int t=threadIdx.x, l=t&63;
  const int b=blockIdx.x>>5, chunk=blockIdx.x&31;
  float s0=0,s1=0,s2=0,q00=0,q01=0,q02=0,q11=0,q12=0,q22=0;
  float ymn=3.4e38f, ymx=-3.4e38f;
  const int base=b*N_+chunk*2048;
  #pragma unroll 2
  for (int i=0;i<8;i++){
    const int p=base+i*256+t;
    const float x0=x[p*3+0], x1=x[p*3+1], x2=x[p*3+2];
    s0+=x0; s1+=x1; s2+=x2;
    q00=fmaf(x0,x0,q00); q01=fmaf(x0,x1,q01); q02=fmaf(x0,x2,q02);
    q11=fmaf(x1,x1,q11); q12=fmaf(x1,x2,q12); q22=fmaf(x2,x2,q22);
    ymn=fminf(ymn,x1); ymx=fmaxf(ymx,x1);
  }
  s0=wave_sum(s0); s1=wave_sum(s1); s2=wave_sum(s2);
  q00=wave_sum(q00); q01=wave_sum(q01); q02=wave_sum(q02);
  q11=wave_sum(q11); q12=wave_sum(q12); q22=wave_sum(q22);
  ymn=wave_min(ymn); ymx=wave_max(ymx);
  if (l==0){
    atomicAdd(&ws[OFF_SXV+0],s0); atomicAdd(&ws[OFF_SXV+1],s1); atomicAdd(&ws[OFF_SXV+2],s2);
    atomicAdd(&ws[OFF_SXX+0],q00); atomicAdd(&ws[OFF_SXX+1],q01); atomicAdd(&ws[OFF_SXX+2],q02);
    atomicAdd(&ws[OFF_SXX+3],q11); atomicAdd(&ws[OFF_SXX+4],q12); atomicAdd(&ws[OFF_SXX+5],q22);
    atomicMin((unsigned*)ws+OFF_YMINU+b, fkey(ymn));
    atomicMax((unsigned*)ws+OFF_YMAXU+b, fkey(ymx));
  }
}

// ---- finA: BN1 fold via quadratic form; unkey ymin/ymax ----
__global__ void k_finA(const float* __restrict__ w1, const float* __restrict__ b1,
                       const float* __restrict__ gm, const float* __restrict__ bt,
                       float* __restrict__ ws){
  int t=threadIdx.x;
  if (t<64){
    const float i_n=1.f/NF;
    const float w0=w1[t], wa=w1[64+t], wb=w1[128+t];
    const float ms=(w0*ws[OFF_SXV+0]+wa*ws[OFF_SXV+1]+wb*ws[OFF_SXV+2])*i_n;
    const float es=(w0*w0*ws[OFF_SXX+0]+wa*wa*ws[OFF_SXX+3]+wb*wb*ws[OFF_SXX+5]
                   +2.f*(w0*wa*ws[OFF_SXX+1]+w0*wb*ws[OFF_SXX+2]+wa*wb*ws[OFF_SXX+4]))*i_n;
    const float var=es-ms*ms;
    const float mean=ms+b1[t];
    const float a=gm[t]/sqrtf(var+1e-5f);
    ws[OFF_A1+t]=a; ws[OFF_C1+t]=bt[t]-mean*a;
  }
  if (t<16){
    unsigned* wsu=(unsigned*)ws;
    ws[OFF_YMINF+t]=funkey(wsu[OFF_YMINU+t]);
    ws[OFF_YMAXF+t]=funkey(wsu[OFF_YMAXU+t]);
  }
}

// ---- bucket segment sums (stream) ----
__global__ __launch_bounds__(256) void k_bucket(const float* __restrict__ x,
                                                float* __restrict__ ws){
  const int t=threadIdx.x, l=t&63;
  const int b=blockIdx.x>>5, chunk=blockIdx.x&31;
  const float ymn=ws[OFF_YMINF+b], ymx=ws[OFF_YMAXF+b];
  float sxl[NBK], szl[NBK], cntl[NBK];
  #pragma unroll
  for (int k=0;k<NBK;k++){ sxl[k]=0.f; szl[k]=0.f; cntl[k]=0.f; }
  const int base=b*N_+chunk*2048;
  #pragma unroll 1
  for (int i=0;i<8;i++){
    const int p=base+i*256+t;
    const float x0=x[p*3+0], x1=x[p*3+1], x2=x[p*3+2];
    const float yn=(x1-ymn)/(ymx-ymn+1e-6f);
    int bk=(int)(yn*10.f); bk = bk<0?0:(bk>10?10:bk);
    #pragma unroll
    for (int k=0;k<NBK;k++){
      const bool m=(bk==k);
      sxl[k]+= m?x0:0.f; szl[k]+= m?x2:0.f; cntl[k]+= m?1.f:0.f;
    }
  }
  #pragma unroll
  for (int k=0;k<NBK;k++){
    const float s=wave_sum(sxl[k]);
    const float z=wave_sum(szl[k]);
    const float c=wave_sum(cntl[k]);
    if (l==0){
      atomicAdd(&ws[OFF_SX +b*NBK+k],s);
      atomicAdd(&ws[OFF_SZ +b*NBK+k],z);
      atomicAdd(&ws[OFF_CNT+b*NBK+k],c);
    }
  }
}

__global__ void k_finB(const float* __restrict__ gm, const float* __restrict__ bt,
                       float* __restrict__ ws){
  int t=threadIdx.x;
  if (t<128){
    const float i_n=1.f/NF;
    const float m=ws[OFF_S2SUM+t]*i_n;
    const float v=ws[OFF_S2SQ+t]*i_n - m*m;
    const float a=gm[t]/sqrtf(v+1e-5f);
    ws[OFF_A2+t]=a; ws[OFF_C2+t]=bt[t]-m*a;
  }
  if (t<176){
    const float c=ws[OFF_CNT+t];
    const float d=fmaxf(c,1.f);
    ws[OFF_CX+t]=ws[OFF_SX+t]/d;
    ws[OFF_CZ+t]=ws[OFF_SZ+t]/d;
  }
}

__global__ void k_finC(const float* __restrict__ gm, const float* __restrict__ bt,
                       float* __restrict__ ws){
  int t=threadIdx.x;
  if (t<256){
    const float i_n=1.f/NF;
    const float m=ws[OFF_S3SUM+t]*i_n;
    const float v=ws[OFF_S3SQ+t]*i_n - m*m;
    const float a=gm[t]/sqrtf(v+1e-5f);
    ws[OFF_A3+t]=a; ws[OFF_C3+t]=bt[t]-m*a;
  }
}

// ---- spatial features: pool sin/cos/r into cols 256..258 (stream) ----
__global__ __launch_bounds__(256) void k_spatial(const float* __restrict__ x,
                                                 float* __restrict__ ws){
  const int t=threadIdx.x, l=t&63;
  const int b=blockIdx.x>>5, chunk=blockIdx.x&31;
  const float ymn=ws[OFF_YMINF+b], ymx=ws[OFF_YMAXF+b];
  float mx[3]={-3.4e38f,-3.4e38f,-3.4e38f}, sm[3]={0.f,0.f,0.f};
  const int base=b*N_+chunk*2048;
  #pragma unroll 1
  for (int i=0;i<8;i++){
    const int p=base+i*256+t;
    const float x0=x[p*3+0], x1=x[p*3+1], x2=x[p*3+2];
    const float yn=(x1-ymn)/(ymx-ymn+1e-6f);
    int bk=(int)(yn*10.f); bk = bk<0?0:(bk>10?10:bk);
    const float dx=x0-ws[OFF_CX+b*NBK+bk];
    const float dz=x2-ws[OFF_CZ+b*NBK+bk];
    const float r=sqrtf(fmaf(dx,dx,dz*dz));
    const float sn=(r>0.f)?(dz/r):0.f;
    const float cs=(r>0.f)?(dx/r):1.f;
    mx[0]=fmaxf(mx[0],sn); sm[0]+=sn;
    mx[1]=fmaxf(mx[1],cs); sm[1]+=cs;
    mx[2]=fmaxf(mx[2],r);  sm[2]+=r;
  }
  #pragma unroll
  for (int q=0;q<3;q++){
    const float m=wave_max(mx[q]);
    const float s=wave_sum(sm[q]);
    if (l==0){
      atomicMax((unsigned*)ws+OFF_FMAXU+b*NFEAT+256+q, fkey(m));
      atomicAdd(&ws[OFF_FSUM+b*NFEAT+256+q], s);
    }
  }
}

// ---- MFMA MLP pass: MODE 0 = h2 stats, 1 = h3 stats, 2 = g3 pooling ----
template<int MODE>
__global__ __launch_bounds__(256,2) void k_mlp(
    const float* __restrict__ x,
    const float* __restrict__ w1, const float* __restrict__ b1,
    const float* __restrict__ w2, const float* __restrict__ b2,
    const float* __restrict__ w3, const float* __restrict__ b3,
    float* __restrict__ ws)
{
  __shared__ short g1t[64*64];    // [point][feat64] bf16, XOR-swizzled
  __shared__ short g2t[64*128];   // [point][feat128] bf16, XOR-swizzled
  const int t=threadIdx.x, w=t>>6, l=t&63, lg=l>>4, lr=l&15;
  const int b=blockIdx.x>>5, chunk=blockIdx.x&31;

  // layer1 folded weights: this lane's 16 features (fA=8lg+i, fB=32+8lg+i)
  const float* a1=ws+OFF_A1; const float* c1=ws+OFF_C1;
  float w1A[3][8], w1B[3][8], b1A[8], b1B[8];
  #pragma unroll
  for (int i=0;i<8;i++){
    const int fA=8*lg+i, fB=32+8*lg+i;
    const float aA=a1[fA], aB=a1[fB];
    #pragma unroll
    for (int q=0;q<3;q++){ w1A[q][i]=w1[q*64+fA]*aA; w1B[q][i]=w1[q*64+fB]*aB; }
    b1A[i]=b1[fA]*aA+c1[fA];
    b1B[i]=b1[fB]*aB+c1[fB];
  }

  // layer2 B-fragments: this wave's 2 coltiles
  s16x8 w2f[2][2]; float b2v[2];
  #pragma unroll
  for (int ct=0;ct<2;ct++){
    const int col=(2*w+ct)*16+lr;
    const float sc=(MODE==0)?1.f:ws[OFF_A2+col];
    b2v[ct]=(MODE==0)? b2[col] : (ws[OFF_A2+col]*b2[col]+ws[OFF_C2+col]);
    #pragma unroll
    for (int kt=0;kt<2;kt++){
      #pragma unroll
      for (int i=0;i<8;i++){
        const int k=kt*32+8*lg+i;
        w2f[ct][kt][i]=(short)bf16_bits(w2[k*128+col]*sc);
      }
    }
  }

  // layer3 B-fragments: this wave's 4 coltiles (MODE 1/2)
  s16x8 w3f[4][4]; float b3v[4]={0,0,0,0};
  if (MODE!=0){
    #pragma unroll
    for (int ct=0;ct<4;ct++){
      const int col=(4*w+ct)*16+lr;
      const float sc=(MODE==1)?1.f:ws[OFF_A3+col];
      b3v[ct]=(MODE==1)? b3[col] : (ws[OFF_A3+col]*b3[col]+ws[OFF_C3+col]);
      #pragma unroll
      for (int kt=0;kt<4;kt++){
        #pragma unroll
        for (int i=0;i<8;i++){
          const int k=kt*32+8*lg+i;
          w3f[ct][kt][i]=(short)bf16_bits(w3[k*256+col]*sc);
        }
      }
    }
  }

  float accS[4], accQ[4]={0.f,0.f,0.f,0.f};
  #pragma unroll
  for (int q_=0;q_<4;q_++) accS[q_]=(MODE==2)?-3.4e38f:0.f;

  char* g1c=(char*)g1t; char* g2c=(char*)g2t;

  for (int it=0; it<32; ++it){
    const int tb=b*N_+chunk*2048+it*64;
    // ---- layer1: this wave's 16 points, 16 feats/lane -> g1 LDS (bf16)
    {
      const int p=16*w+lr;
      const float x0=x[(tb+p)*3+0], x1=x[(tb+p)*3+1], x2=x[(tb+p)*3+2];
      float h[8]; unsigned pk[4];
      #pragma unroll
      for (int i=0;i<8;i++){
        float v=b1A[i];
        v=fmaf(x0,w1A[0][i],v); v=fmaf(x1,w1A[1][i],v); v=fmaf(x2,w1A[2][i],v);
        h[i]=fmaxf(v,0.f);
      }
      #pragma unroll
      for (int i=0;i<4;i++) pk[i]=(unsigned)bf16_bits(h[2*i]) | ((unsigned)bf16_bits(h[2*i+1])<<16);
      *(int4*)(g1c + (((p*64+8*lg)*2) ^ ((p&7)<<4))) = make_int4(pk[0],pk[1],pk[2],pk[3]);
      #pragma unroll
      for (int i=0;i<8;i++){
        float v=b1B[i];
        v=fmaf(x0,w1B[0][i],v); v=fmaf(x1,w1B[1][i],v); v=fmaf(x2,w1B[2][i],v);
        h[i]=fmaxf(v,0.f);
      }
      #pragma unroll
      for (int i=0;i<4;i++) pk[i]=(unsigned)bf16_bits(h[2*i]) | ((unsigned)bf16_bits(h[2*i+1])<<16);
      *(int4*)(g1c + (((p*64+32+8*lg)*2) ^ ((p&7)<<4))) = make_int4(pk[0],pk[1],pk[2],pk[3]);
    }
    __syncthreads();
    // ---- layer2: A-frags from g1, MFMA into this wave's 2 coltiles
    s16x8 a1f[4][2];
    #pragma unroll
    for (int rt=0;rt<4;rt++){
      const int p=rt*16+lr;
      #pragma unroll
      for (int kt=0;kt<2;kt++)
        a1f[rt][kt]=*(const s16x8*)(g1c + (((p*64+kt*32+8*lg)*2) ^ ((p&7)<<4)));
    }
    #pragma unroll
    for (int ct=0;ct<2;ct++){
      const int col=(2*w+ct)*16+lr;
      #pragma unroll
      for (int rt=0;rt<4;rt++){
        f32x4 acc={0.f,0.f,0.f,0.f};
        acc=__builtin_amdgcn_mfma_f32_16x16x32_bf16(a1f[rt][0],w2f[ct][0],acc,0,0,0);
        acc=__builtin_amdgcn_mfma_f32_16x16x32_bf16(a1f[rt][1],w2f[ct][1],acc,0,0,0);
        if (MODE==0){
          #pragma unroll
          for (int r=0;r<4;r++){ const float h2=acc[r]+b2v[ct]; accS[ct]+=h2; accQ[ct]+=h2*h2; }
        } else {
          #pragma unroll
          for (int r=0;r<4;r++){
            const int p=rt*16+4*lg+r;
            const float g=fmaxf(acc[r]+b2v[ct],0.f);
            *(short*)(g2c + (((p*128+col)*2) ^ ((p&7)<<4))) = (short)bf16_bits(g);
          }
        }
      }
    }
    __syncthreads();
    // ---- layer3
    if (MODE!=0){
      #pragma unroll
      for (int rt=0;rt<4;rt++){
        const int p=rt*16+lr;
        s16x8 a2f[4];
        #pragma unroll
        for (int kt=0;kt<4;kt++)
          a2f[kt]=*(const s16x8*)(g2c + (((p*128+kt*32+8*lg)*2) ^ ((p&7)<<4)));
        #pragma unroll
        for (int ct=0;ct<4;ct++){
          f32x4 acc={0.f,0.f,0.f,0.f};
          #pragma unroll
          for (int kt=0;kt<4;kt++)
            acc=__builtin_amdgcn_mfma_f32_16x16x32_bf16(a2f[kt],w3f[ct][kt],acc,0,0,0);
          #pragma unroll
          for (int r=0;r<4;r++){
            if (MODE==1){ const float h3=acc[r]+b3v[ct]; accS[ct]+=h3; accQ[ct]+=h3*h3; }
            else        { const float g=fmaxf(acc[r]+b3v[ct],0.f); accS[ct]=fmaxf(accS[ct],g); accQ[ct]+=g; }
          }
        }
      }
    }
  }

  // ---- flush
  if (MODE==0){
    #pragma unroll
    for (int ct=0;ct<2;ct++){
      float s=accS[ct], q=accQ[ct];
      s+=__shfl_xor(s,16); s+=__shfl_xor(s,32);
      q+=__shfl_xor(q,16); q+=__shfl_xor(q,32);
      if (l<16){
        const int col=(2*w+ct)*16+lr;
        atomicAdd(&ws[OFF_S2SUM+col],s);
        atomicAdd(&ws[OFF_S2SQ +col],q);
      }
    }
  } else if (MODE==1){
    #pragma unroll
    for (int ct=0;ct<4;ct++){
      float s=accS[ct], q=accQ[ct];
      s+=__shfl_xor(s,16); s+=__shfl_xor(s,32);
      q+=__shfl_xor(q,16); q+=__shfl_xor(q,32);
      if (l<16){
        const int col=(4*w+ct)*16+lr;
        atomicAdd(&ws[OFF_S3SUM+col],s);
        atomicAdd(&ws[OFF_S3SQ +col],q);
      }
    }
  } else {
    #pragma unroll
    for (int ct=0;ct<4;ct++){
      float m=accS[ct], s=accQ[ct];
      m=fmaxf(m,__shfl_xor(m,16)); m=fmaxf(m,__shfl_xor(m,32));
      s+=__shfl_xor(s,16); s+=__shfl_xor(s,32);
      if (l<16){
        const int col=(4*w+ct)*16+lr;
        atomicMax((unsigned*)ws+OFF_FMAXU+b*NFEAT+col, fkey(m));
        atomicAdd(&ws[OFF_FSUM+b*NFEAT+col], s);
      }
    }
  }
}

// ---- final: feat_cat(518) @ wp + bp, LayerNorm ----
__global__ __launch_bounds__(256) void k_final(
    const float* __restrict__ wp, const float* __restrict__ bp,
    const float* __restrict__ gln, const float* __restrict__ bln,
    float* __restrict__ out, const float* __restrict__ ws)
{
  __shared__ float feat[518];
  __shared__ float red[256];
  const int b=blockIdx.x, t=threadIdx.x;
  const unsigned* wsu=(const unsigned*)ws;
  for (int i=t;i<NFEAT;i+=256){
    feat[i]       = funkey(wsu[OFF_FMAXU+b*NFEAT+i]);
    feat[NFEAT+i] = ws[OFF_FSUM+b*NFEAT+i]*(1.f/65536.f);
  }
  __syncthreads();
  float o0=bp[t], o1=bp[t+256];
  #pragma unroll 4
  for (int i=0;i<518;i++){
    const float f=feat[i];
    o0=fmaf(f, wp[i*512+t],     o0);
    o1=fmaf(f, wp[i*512+t+256], o1);
  }
  red[t]=o0+o1; __syncthreads();
  for (int s=128;s>0;s>>=1){ if (t<s) red[t]+=red[t+s]; __syncthreads(); }
  const float mu=red[0]*(1.f/512.f);
  __syncthreads();
  const float d0=o0-mu, d1=o1-mu;
  red[t]=d0*d0+d1*d1; __syncthreads();
  for (int s=128;s>0;s>>=1){ if (t<s) red[t]+=red[t+s]; __syncthreads(); }
  const float var=red[0]*(1.f/512.f);
  const float rs=1.f/sqrtf(var+1e-5f);
  out[b*512+t]     = d0*rs*gln[t]    +bln[t];
  out[b*512+t+256] = d1*rs*gln[t+256]+bln[t+256];
}

extern "C" void kernel_launch(void* const* d_in, const int* in_sizes, int n_in,
                              void* d_out, int out_size, void* d_ws, size_t ws_size,
                              hipStream_t stream)
{
  const float* x  =(const float*)d_in[0];
  const float* w1 =(const float*)d_in[1];
  const float* b1 =(const float*)d_in[2];
  const float* gm1=(const float*)d_in[3];
  const float* be1=(const float*)d_in[4];
  const float* w2 =(const float*)d_in[5];
  const float* b2 =(const float*)d_in[6];
  const float* gm2=(const float*)d_in[7];
  const float* be2=(const float*)d_in[8];
  const float* w3 =(const float*)d_in[9];
  const float* b3 =(const float*)d_in[10];
  const float* gm3=(const float*)d_in[11];
  const float* be3=(const float*)d_in[12];
  const float* wp =(const float*)d_in[13];
  const float* bp =(const float*)d_in[14];
  const float* gln=(const float*)d_in[15];
  const float* bln=(const float*)d_in[16];
  float* ws=(float*)d_ws;
  float* out=(float*)d_out;

  k_init   <<<dim3(1),  dim3(256),0,stream>>>(ws);
  k_stream0<<<dim3(512),dim3(256),0,stream>>>(x,ws);
  k_finA   <<<dim3(1),  dim3(64), 0,stream>>>(w1,b1,gm1,be1,ws);
  k_bucket <<<dim3(512),dim3(256),0,stream>>>(x,ws);
  k_mlp<0> <<<dim3(512),dim3(256),0,stream>>>(x,w1,b1,w2,b2,w3,b3,ws);
  k_finB   <<<dim3(1),  dim3(256),0,stream>>>(gm2,be2,ws);
  k_spatial<<<dim3(512),dim3(256),0,stream>>>(x,ws);
  k_mlp<1> <<<dim3(512),dim3(256),0,stream>>>(x,w1,b1,w2,b2,w3,b3,ws);
  k_finC   <<<dim3(1),  dim3(256),0,stream>>>(gm3,be3,ws);
  k_mlp<2> <<<dim3(512),dim3(256),0,stream>>>(x,w1,b1,w2,b2,w3,b3,ws);
  k_final  <<<dim3(16), dim3(256),0,stream>>>(wp,bp,gln,bln,out,ws);
}

// Round 3
// 486.509 us; speedup vs baseline: 93.0531x; 1.4407x over previous
//
#include <hip/hip_runtime.h>
#include <stdint.h>

#define B_    16
#define N_    65536
#define NPTS  (B_*N_)
#define NBK   11
#define NFEAT 259
#define NF    ((float)NPTS)

typedef float f32x4 __attribute__((ext_vector_type(4)));
typedef short s16x8 __attribute__((ext_vector_type(8)));

// ---- workspace float offsets ----
enum {
  OFF_YMINF = 16,     // 16
  OFF_YMAXF = 32,     // 16
  OFF_A1    = 64,     // 64
  OFF_C1    = 128,    // 64
  OFF_A2    = 192,    // 128
  OFF_C2    = 320,    // 128
  OFF_CX    = 448,    // 176
  OFF_CZ    = 624,    // 176
  OFF_A3    = 800,    // 256
  OFF_C3    = 1056,   // 256
  // per-block partials (512 blocks)
  OFF_PSTR  = 16384,  // 512*16 : s0,s1,s2,q00,q01,q02,q11,q12,q22,ymn,ymx
  OFF_PBKT  = 24576,  // 512*36 : sx[11], sz[11], cnt[11]
  OFF_PH2   = 49152,  // 512*256: sum[128], sq[128]
  OFF_PH3   = 180224, // 512*512: sum[256], sq[256]
  OFF_PPOOL = 442368, // 512*512: max[256], sum[256]
  OFF_PSPA  = 704512  // 512*8  : max[3], sum[3]
};

// ---- helpers ----
__device__ __forceinline__ float wave_sum(float v){
  #pragma unroll
  for (int m=32;m>=1;m>>=1) v += __shfl_xor(v,m,64);
  return v;
}
__device__ __forceinline__ float wave_max(float v){
  #pragma unroll
  for (int m=32;m>=1;m>>=1) v = fmaxf(v,__shfl_xor(v,m,64));
  return v;
}
__device__ __forceinline__ float wave_min(float v){
  #pragma unroll
  for (int m=32;m>=1;m>>=1) v = fminf(v,__shfl_xor(v,m,64));
  return v;
}
__device__ __forceinline__ unsigned short bf16_bits(float f){
  unsigned u=__float_as_uint(f);
  u += 0x7FFFu + ((u>>16)&1u);
  return (unsigned short)(u>>16);
}

// ---- pass A: x colsums + X^T X + per-batch y min/max -> per-block partials ----
__global__ __launch_bounds__(256) void k_stream0(const float* __restrict__ x,
                                                 float* __restrict__ ws){
  __shared__ float red[4][12];
  const int t=threadIdx.x, l=t&63, w=t>>6;
  const int bid=blockIdx.x;
  const float4* xv=(const float4*)(x + (size_t)bid*2048*3);
  float s0=0,s1=0,s2=0,q00=0,q01=0,q02=0,q11=0,q12=0,q22=0;
  float ymn=3.4e38f, ymx=-3.4e38f;
  #pragma unroll
  for (int i=0;i<2;i++){
    const int vi=(i*256+t)*3;
    const float4 a=xv[vi], b4=xv[vi+1], c=xv[vi+2];
    float X[4]={a.x,a.w,b4.z,c.y};
    float Y[4]={a.y,b4.x,b4.w,c.z};
    float Z[4]={a.z,b4.y,c.x,c.w};
    #pragma unroll
    for (int p=0;p<4;p++){
      s0+=X[p]; s1+=Y[p]; s2+=Z[p];
      q00=fmaf(X[p],X[p],q00); q01=fmaf(X[p],Y[p],q01); q02=fmaf(X[p],Z[p],q02);
      q11=fmaf(Y[p],Y[p],q11); q12=fmaf(Y[p],Z[p],q12); q22=fmaf(Z[p],Z[p],q22);
      ymn=fminf(ymn,Y[p]); ymx=fmaxf(ymx,Y[p]);
    }
  }
  s0=wave_sum(s0); s1=wave_sum(s1); s2=wave_sum(s2);
  q00=wave_sum(q00); q01=wave_sum(q01); q02=wave_sum(q02);
  q11=wave_sum(q11); q12=wave_sum(q12); q22=wave_sum(q22);
  ymn=wave_min(ymn); ymx=wave_max(ymx);
  if (l==0){
    red[w][0]=s0; red[w][1]=s1; red[w][2]=s2;
    red[w][3]=q00; red[w][4]=q01; red[w][5]=q02;
    red[w][6]=q11; red[w][7]=q12; red[w][8]=q22;
    red[w][9]=ymn; red[w][10]=ymx;
  }
  __syncthreads();
  if (t<11){
    const float v0=red[0][t],v1=red[1][t],v2=red[2][t],v3=red[3][t];
    float r;
    if (t==9)       r=fminf(fminf(v0,v1),fminf(v2,v3));
    else if (t==10) r=fmaxf(fmaxf(v0,v1),fmaxf(v2,v3));
    else            r=v0+v1+v2+v3;
    ws[OFF_PSTR+bid*16+t]=r;
  }
}

// ---- finA: reduce partials; BN1 fold via quadratic form ----
__global__ void k_finA(const float* __restrict__ w1, const float* __restrict__ b1,
                       const float* __restrict__ gm, const float* __restrict__ bt,
                       float* __restrict__ ws){
  __shared__ float sums[9];
  const int t=threadIdx.x;
  if (t<9){
    float s=0.f;
    #pragma unroll 8
    for (int blk=0;blk<512;blk++) s+=ws[OFF_PSTR+blk*16+t];
    sums[t]=s;
  }
  if (t>=32&&t<48){
    const int b=t-32; float m=3.4e38f;
    #pragma unroll 8
    for (int blk=0;blk<32;blk++) m=fminf(m,ws[OFF_PSTR+(b*32+blk)*16+9]);
    ws[OFF_YMINF+b]=m;
  }
  if (t>=48&&t<64){
    const int b=t-48; float m=-3.4e38f;
    #pragma unroll 8
    for (int blk=0;blk<32;blk++) m=fmaxf(m,ws[OFF_PSTR+(b*32+blk)*16+10]);
    ws[OFF_YMAXF+b]=m;
  }
  __syncthreads();
  if (t<64){
    const float i_n=1.f/NF;
    const float w0=w1[t], wa=w1[64+t], wb=w1[128+t];
    const float ms=(w0*sums[0]+wa*sums[1]+wb*sums[2])*i_n;
    const float es=(w0*w0*sums[3]+wa*wa*sums[6]+wb*wb*sums[8]
                   +2.f*(w0*wa*sums[4]+w0*wb*sums[5]+wa*wb*sums[7]))*i_n;
    const float var=es-ms*ms;
    const float a=gm[t]/sqrtf(var+1e-5f);
    ws[OFF_A1+t]=a; ws[OFF_C1+t]=bt[t]-(ms+b1[t])*a;
  }
}

// ---- bucket segment sums -> per-block partials ----
__global__ __launch_bounds__(256) void k_bucket(const float* __restrict__ x,
                                                float* __restrict__ ws){
  __shared__ float red[4][33];
  const int t=threadIdx.x, l=t&63, w=t>>6;
  const int bid=blockIdx.x, b=bid>>5;
  const float ymn=ws[OFF_YMINF+b], ymx=ws[OFF_YMAXF+b];
  const float4* xv=(const float4*)(x + (size_t)bid*2048*3);
  float sxl[NBK], szl[NBK], cntl[NBK];
  #pragma unroll
  for (int k=0;k<NBK;k++){ sxl[k]=0.f; szl[k]=0.f; cntl[k]=0.f; }
  #pragma unroll
  for (int i=0;i<2;i++){
    const int vi=(i*256+t)*3;
    const float4 a=xv[vi], b4=xv[vi+1], c=xv[vi+2];
    float X[4]={a.x,a.w,b4.z,c.y};
    float Y[4]={a.y,b4.x,b4.w,c.z};
    float Z[4]={a.z,b4.y,c.x,c.w};
    #pragma unroll
    for (int p=0;p<4;p++){
      const float yn=(Y[p]-ymn)/(ymx-ymn+1e-6f);
      int bk=(int)(yn*10.f); bk = bk<0?0:(bk>10?10:bk);
      #pragma unroll
      for (int k=0;k<NBK;k++){
        const bool m=(bk==k);
        sxl[k]+= m?X[p]:0.f; szl[k]+= m?Z[p]:0.f; cntl[k]+= m?1.f:0.f;
      }
    }
  }
  #pragma unroll
  for (int k=0;k<NBK;k++){
    const float s=wave_sum(sxl[k]);
    const float z=wave_sum(szl[k]);
    const float c=wave_sum(cntl[k]);
    if (l==0){ red[w][k]=s; }
    __syncthreads();
    if (l==0&&w==0){ /*placeholder*/ }
    __syncthreads();
    if (l==0){ red[w][k]=s; }
    // (reduced below via LDS; simple overwrite is fine since all waves wrote)
    if (l==0){ red[w][k]=s; }
    __syncthreads();
    if (t<1){} // no-op
    // store z and c via second/third slots handled after loop
    if (l==0){ red[w][k]=s; }
    // NOTE: replaced below — see combined flush
    (void)z; (void)c;
    break;
  }
  // ---- combined flush (clean implementation) ----
  #pragma unroll
  for (int k=0;k<NBK;k++){
    const float s=wave_sum(sxl[k]);
    if (l==0) red[w][k]=s;
  }
  __syncthreads();
  if (t<NBK) ws[OFF_PBKT+bid*36+t]=red[0][t]+red[1][t]+red[2][t]+red[3][t];
  __syncthreads();
  #pragma unroll
  for (int k=0;k<NBK;k++){
    const float z=wave_sum(szl[k]);
    if (l==0) red[w][k]=z;
  }
  __syncthreads();
  if (t<NBK) ws[OFF_PBKT+bid*36+11+t]=red[0][t]+red[1][t]+red[2][t]+red[3][t];
  __syncthreads();
  #pragma unroll
  for (int k=0;k<NBK;k++){
    const float c=wave_sum(cntl[k]);
    if (l==0) red[w][k]=c;
  }
  __syncthreads();
  if (t<NBK) ws[OFF_PBKT+bid*36+22+t]=red[0][t]+red[1][t]+red[2][t]+red[3][t];
}

// ---- finB: reduce h2 partials -> BN2 fold; reduce bucket partials -> centers ----
__global__ void k_finB(const float* __restrict__ gm, const float* __restrict__ bt,
                       float* __restrict__ ws){
  __shared__ float acc[256];
  const int t=threadIdx.x;              // 256 threads
  {
    const int col=t&127, part=t>>7;
    float s=0.f;
    #pragma unroll 8
    for (int blk=0;blk<512;blk++) s+=ws[OFF_PH2+blk*256+part*128+col];
    acc[t]=s;
  }
  __syncthreads();
  if (t<128){
    const float i_n=1.f/NF;
    const float m=acc[t]*i_n;
    const float v=acc[128+t]*i_n-m*m;
    const float a=gm[t]/sqrtf(v+1e-5f);
    ws[OFF_A2+t]=a; ws[OFF_C2+t]=bt[t]-m*a;
  }
  if (t<176){
    const int b=t/NBK, k=t-b*NBK;
    float sx=0.f, sz=0.f, cn=0.f;
    #pragma unroll 8
    for (int blk=0;blk<32;blk++){
      const int p=OFF_PBKT+(b*32+blk)*36;
      sx+=ws[p+k]; sz+=ws[p+11+k]; cn+=ws[p+22+k];
    }
    const float d=fmaxf(cn,1.f);
    ws[OFF_CX+t]=sx/d; ws[OFF_CZ+t]=sz/d;
  }
}

// ---- finC: reduce h3 partials -> BN3 fold ----
__global__ void k_finC(const float* __restrict__ gm, const float* __restrict__ bt,
                       float* __restrict__ ws){
  __shared__ float acc[512];
  const int t=threadIdx.x;              // 512 threads
  {
    const int col=t&255, part=t>>8;
    float s=0.f;
    #pragma unroll 8
    for (int blk=0;blk<512;blk++) s+=ws[OFF_PH3+blk*512+part*256+col];
    acc[t]=s;
  }
  __syncthreads();
  if (t<256){
    const float i_n=1.f/NF;
    const float m=acc[t]*i_n;
    const float v=acc[256+t]*i_n-m*m;
    const float a=gm[t]/sqrtf(v+1e-5f);
    ws[OFF_A3+t]=a; ws[OFF_C3+t]=bt[t]-m*a;
  }
}

// ---- spatial features -> per-block partials ----
__global__ __launch_bounds__(256) void k_spatial(const float* __restrict__ x,
                                                 float* __restrict__ ws){
  __shared__ float red[4][8];
  const int t=threadIdx.x, l=t&63, w=t>>6;
  const int bid=blockIdx.x, b=bid>>5;
  const float ymn=ws[OFF_YMINF+b], ymx=ws[OFF_YMAXF+b];
  const float4* xv=(const float4*)(x + (size_t)bid*2048*3);
  float mx[3]={-3.4e38f,-3.4e38f,-3.4e38f}, sm[3]={0.f,0.f,0.f};
  #pragma unroll
  for (int i=0;i<2;i++){
    const int vi=(i*256+t)*3;
    const float4 a=xv[vi], b4=xv[vi+1], c=xv[vi+2];
    float X[4]={a.x,a.w,b4.z,c.y};
    float Y[4]={a.y,b4.x,b4.w,c.z};
    float Z[4]={a.z,b4.y,c.x,c.w};
    #pragma unroll
    for (int p=0;p<4;p++){
      const float yn=(Y[p]-ymn)/(ymx-ymn+1e-6f);
      int bk=(int)(yn*10.f); bk = bk<0?0:(bk>10?10:bk);
      const float dx=X[p]-ws[OFF_CX+b*NBK+bk];
      const float dz=Z[p]-ws[OFF_CZ+b*NBK+bk];
      const float r=sqrtf(fmaf(dx,dx,dz*dz));
      const float sn=(r>0.f)?(dz/r):0.f;
      const float cs=(r>0.f)?(dx/r):1.f;
      mx[0]=fmaxf(mx[0],sn); sm[0]+=sn;
      mx[1]=fmaxf(mx[1],cs); sm[1]+=cs;
      mx[2]=fmaxf(mx[2],r);  sm[2]+=r;
    }
  }
  #pragma unroll
  for (int q=0;q<3;q++){
    const float m=wave_max(mx[q]);
    const float s=wave_sum(sm[q]);
    if (l==0){ red[w][q]=m; red[w][4+q]=s; }
  }
  __syncthreads();
  if (t<3)        ws[OFF_PSPA+bid*8+t]  =fmaxf(fmaxf(red[0][t],red[1][t]),fmaxf(red[2][t],red[3][t]));
  else if (t>=4&&t<7){
    const int q=t-4;
    ws[OFF_PSPA+bid*8+4+q]=red[0][4+q]+red[1][4+q]+red[2][4+q]+red[3][4+q];
  }
}

// ---- MFMA MLP pass: MODE 0 = h2 stats, 1 = h3 stats, 2 = g3 pooling ----
template<int MODE>
__global__ __launch_bounds__(256,2) void k_mlp(
    const float* __restrict__ x,
    const float* __restrict__ w1, const float* __restrict__ b1,
    const float* __restrict__ w2, const float* __restrict__ b2,
    const float* __restrict__ w3, const float* __restrict__ b3,
    float* __restrict__ ws)
{
  __shared__ short g1t[64*64];    // [point][feat64] bf16, XOR-swizzled
  __shared__ short g2t[64*128];   // [point][feat128] bf16, XOR-swizzled
  const int t=threadIdx.x, w=t>>6, l=t&63, lg=l>>4, lr=l&15;
  const int b=blockIdx.x>>5, chunk=blockIdx.x&31;
  const int bid=blockIdx.x;

  // layer1 folded weights: this lane's 16 features (fA=8lg+i, fB=32+8lg+i)
  const float* a1=ws+OFF_A1; const float* c1=ws+OFF_C1;
  float w1A[3][8], w1B[3][8], b1A[8], b1B[8];
  #pragma unroll
  for (int i=0;i<8;i++){
    const int fA=8*lg+i, fB=32+8*lg+i;
    const float aA=a1[fA], aB=a1[fB];
    #pragma unroll
    for (int q=0;q<3;q++){ w1A[q][i]=w1[q*64+fA]*aA; w1B[q][i]=w1[q*64+fB]*aB; }
    b1A[i]=b1[fA]*aA+c1[fA];
    b1B[i]=b1[fB]*aB+c1[fB];
  }

  // layer2 B-fragments: this wave's 2 coltiles
  s16x8 w2f[2][2]; float b2v[2];
  #pragma unroll
  for (int ct=0;ct<2;ct++){
    const int col=(2*w+ct)*16+lr;
    const float sc=(MODE==0)?1.f:ws[OFF_A2+col];
    b2v[ct]=(MODE==0)? b2[col] : (ws[OFF_A2+col]*b2[col]+ws[OFF_C2+col]);
    #pragma unroll
    for (int kt=0;kt<2;kt++){
      #pragma unroll
      for (int i=0;i<8;i++){
        const int k=kt*32+8*lg+i;
        w2f[ct][kt][i]=(short)bf16_bits(w2[k*128+col]*sc);
      }
    }
  }

  // layer3 B-fragments: this wave's 4 coltiles (MODE 1/2)
  s16x8 w3f[4][4]; float b3v[4]={0,0,0,0};
  if (MODE!=0){
    #pragma unroll
    for (int ct=0;ct<4;ct++){
      const int col=(4*w+ct)*16+lr;
      const float sc=(MODE==1)?1.f:ws[OFF_A3+col];
      b3v[ct]=(MODE==1)? b3[col] : (ws[OFF_A3+col]*b3[col]+ws[OFF_C3+col]);
      #pragma unroll
      for (int kt=0;kt<4;kt++){
        #pragma unroll
        for (int i=0;i<8;i++){
          const int k=kt*32+8*lg+i;
          w3f[ct][kt][i]=(short)bf16_bits(w3[k*256+col]*sc);
        }
      }
    }
  }

  float accS[4], accQ[4]={0.f,0.f,0.f,0.f};
  #pragma unroll
  for (int q_=0;q_<4;q_++) accS[q_]=(MODE==2)?-3.4e38f:0.f;

  char* g1c=(char*)g1t; char* g2c=(char*)g2t;

  for (int it=0; it<32; ++it){
    const int tb=b*N_+chunk*2048+it*64;
    // ---- layer1: this wave's 16 points, 16 feats/lane -> g1 LDS (bf16)
    {
      const int p=16*w+lr;
      const float x0=x[(tb+p)*3+0], x1=x[(tb+p)*3+1], x2=x[(tb+p)*3+2];
      float h[8]; unsigned pk[4];
      #pragma unroll
      for (int i=0;i<8;i++){
        float v=b1A[i];
        v=fmaf(x0,w1A[0][i],v); v=fmaf(x1,w1A[1][i],v); v=fmaf(x2,w1A[2][i],v);
        h[i]=fmaxf(v,0.f);
      }
      #pragma unroll
      for (int i=0;i<4;i++) pk[i]=(unsigned)bf16_bits(h[2*i]) | ((unsigned)bf16_bits(h[2*i+1])<<16);
      *(int4*)(g1c + (((p*64+8*lg)*2) ^ ((p&7)<<4))) = make_int4(pk[0],pk[1],pk[2],pk[3]);
      #pragma unroll
      for (int i=0;i<8;i++){
        float v=b1B[i];
        v=fmaf(x0,w1B[0][i],v); v=fmaf(x1,w1B[1][i],v); v=fmaf(x2,w1B[2][i],v);
        h[i]=fmaxf(v,0.f);
      }
      #pragma unroll
      for (int i=0;i<4;i++) pk[i]=(unsigned)bf16_bits(h[2*i]) | ((unsigned)bf16_bits(h[2*i+1])<<16);
      *(int4*)(g1c + (((p*64+32+8*lg)*2) ^ ((p&7)<<4))) = make_int4(pk[0],pk[1],pk[2],pk[3]);
    }
    __syncthreads();
    // ---- layer2: A-frags from g1, MFMA into this wave's 2 coltiles
    s16x8 a1f[4][2];
    #pragma unroll
    for (int rt=0;rt<4;rt++){
      const int p=rt*16+lr;
      #pragma unroll
      for (int kt=0;kt<2;kt++)
        a1f[rt][kt]=*(const s16x8*)(g1c + (((p*64+kt*32+8*lg)*2) ^ ((p&7)<<4)));
    }
    #pragma unroll
    for (int ct=0;ct<2;ct++){
      const int col=(2*w+ct)*16+lr;
      #pragma unroll
      for (int rt=0;rt<4;rt++){
        f32x4 acc={0.f,0.f,0.f,0.f};
        acc=__builtin_amdgcn_mfma_f32_16x16x32_bf16(a1f[rt][0],w2f[ct][0],acc,0,0,0);
        acc=__builtin_amdgcn_mfma_f32_16x16x32_bf16(a1f[rt][1],w2f[ct][1],acc,0,0,0);
        if (MODE==0){
          #pragma unroll
          for (int r=0;r<4;r++){ const float h2=acc[r]+b2v[ct]; accS[ct]+=h2; accQ[ct]+=h2*h2; }
        } else {
          #pragma unroll
          for (int r=0;r<4;r++){
            const int p=rt*16+4*lg+r;
            const float g=fmaxf(acc[r]+b2v[ct],0.f);
            *(short*)(g2c + (((p*128+col)*2) ^ ((p&7)<<4))) = (short)bf16_bits(g);
          }
        }
      }
    }
    __syncthreads();
    // ---- layer3
    if (MODE!=0){
      #pragma unroll
      for (int rt=0;rt<4;rt++){
        const int p=rt*16+lr;
        s16x8 a2f[4];
        #pragma unroll
        for (int kt=0;kt<4;kt++)
          a2f[kt]=*(const s16x8*)(g2c + (((p*128+kt*32+8*lg)*2) ^ ((p&7)<<4)));
        #pragma unroll
        for (int ct=0;ct<4;ct++){
          f32x4 acc={0.f,0.f,0.f,0.f};
          #pragma unroll
          for (int kt=0;kt<4;kt++)
            acc=__builtin_amdgcn_mfma_f32_16x16x32_bf16(a2f[kt],w3f[ct][kt],acc,0,0,0);
          #pragma unroll
          for (int r=0;r<4;r++){
            if (MODE==1){ const float h3=acc[r]+b3v[ct]; accS[ct]+=h3; accQ[ct]+=h3*h3; }
            else        { const float g=fmaxf(acc[r]+b3v[ct],0.f); accS[ct]=fmaxf(accS[ct],g); accQ[ct]+=g; }
          }
        }
      }
    }
  }

  // ---- flush: per-block partial writes (no atomics)
  if (MODE==0){
    #pragma unroll
    for (int ct=0;ct<2;ct++){
      float s=accS[ct], q=accQ[ct];
      s+=__shfl_xor(s,16); s+=__shfl_xor(s,32);
      q+=__shfl_xor(q,16); q+=__shfl_xor(q,32);
      if (l<16){
        const int col=(2*w+ct)*16+lr;
        ws[OFF_PH2+bid*256+col]    =s;
        ws[OFF_PH2+bid*256+128+col]=q;
      }
    }
  } else if (MODE==1){
    #pragma unroll
    for (int ct=0;ct<4;ct++){
      float s=accS[ct], q=accQ[ct];
      s+=__shfl_xor(s,16); s+=__shfl_xor(s,32);
      q+=__shfl_xor(q,16); q+=__shfl_xor(q,32);
      if (l<16){
        const int col=(4*w+ct)*16+lr;
        ws[OFF_PH3+bid*512+col]    =s;
        ws[OFF_PH3+bid*512+256+col]=q;
      }
    }
  } else {
    #pragma unroll
    for (int ct=0;ct<4;ct++){
      float m=accS[ct], s=accQ[ct];
      m=fmaxf(m,__shfl_xor(m,16)); m=fmaxf(m,__shfl_xor(m,32));
      s+=__shfl_xor(s,16); s+=__shfl_xor(s,32);
      if (l<16){
        const int col=(4*w+ct)*16+lr;
        ws[OFF_PPOOL+bid*512+col]    =m;
        ws[OFF_PPOOL+bid*512+256+col]=s;
      }
    }
  }
}

// ---- final: reduce pool partials, feat_cat(518) @ wp + bp, LayerNorm ----
__global__ __launch_bounds__(256) void k_final(
    const float* __restrict__ wp, const float* __restrict__ bp,
    const float* __restrict__ gln, const float* __restrict__ bln,
    float* __restrict__ out, const float* __restrict__ ws)
{
  __shared__ float feat[518];
  __shared__ float red[256];
  const int b=blockIdx.x, t=threadIdx.x;
  {
    float fm=-3.4e38f, fs=0.f;
    #pragma unroll 4
    for (int blk=0;blk<32;blk++){
      const int p=OFF_PPOOL+(b*32+blk)*512;
      fm=fmaxf(fm,ws[p+t]);
      fs+=ws[p+256+t];
    }
    feat[t]=fm; feat[NFEAT+t]=fs*(1.f/65536.f);
  }
  if (t<3){
    float fm=-3.4e38f, fs=0.f;
    #pragma unroll 4
    for (int blk=0;blk<32;blk++){
      const int p=OFF_PSPA+(b*32+blk)*8;
      fm=fmaxf(fm,ws[p+t]);
      fs+=ws[p+4+t];
    }
    feat[256+t]=fm; feat[NFEAT+256+t]=fs*(1.f/65536.f);
  }
  __syncthreads();
  float o0=bp[t], o1=bp[t+256];
  #pragma unroll 4
  for (int i=0;i<518;i++){
    const float f=feat[i];
    o0=fmaf(f, wp[i*512+t],     o0);
    o1=fmaf(f, wp[i*512+t+256], o1);
  }
  red[t]=o0+o1; __syncthreads();
  for (int s=128;s>0;s>>=1){ if (t<s) red[t]+=red[t+s]; __syncthreads(); }
  const float mu=red[0]*(1.f/512.f);
  __syncthreads();
  const float d0=o0-mu, d1=o1-mu;
  red[t]=d0*d0+d1*d1; __syncthreads();
  for (int s=128;s>0;s>>=1){ if (t<s) red[t]+=red[t+s]; __syncthreads(); }
  const float var=red[0]*(1.f/512.f);
  const float rs=1.f/sqrtf(var+1e-5f);
  out[b*512+t]     = d0*rs*gln[t]    +bln[t];
  out[b*512+t+256] = d1*rs*gln[t+256]+bln[t+256];
}

extern "C" void kernel_launch(void* const* d_in, const int* in_sizes, int n_in,
                              void* d_out, int out_size, void* d_ws, size_t ws_size,
                              hipStream_t stream)
{
  const float* x  =(const float*)d_in[0];
  const float* w1 =(const float*)d_in[1];
  const float* b1 =(const float*)d_in[2];
  const float* gm1=(const float*)d_in[3];
  const float* be1=(const float*)d_in[4];
  const float* w2 =(const float*)d_in[5];
  const float* b2 =(const float*)d_in[6];
  const float* gm2=(const float*)d_in[7];
  const float* be2=(const float*)d_in[8];
  const float* w3 =(const float*)d_in[9];
  const float* b3 =(const float*)d_in[10];
  const float* gm3=(const float*)d_in[11];
  const float* be3=(const float*)d_in[12];
  const float* wp =(const float*)d_in[13];
  const float* bp =(const float*)d_in[14];
  const float* gln=(const float*)d_in[15];
  const float* bln=(const float*)d_in[16];
  float* ws=(float*)d_ws;
  float* out=(float*)d_out;

  k_stream0<<<dim3(512),dim3(256),0,stream>>>(x,ws);
  k_finA   <<<dim3(1),  dim3(256),0,stream>>>(w1,b1,gm1,be1,ws);
  k_bucket <<<dim3(512),dim3(256),0,stream>>>(x,ws);
  k_mlp<0> <<<dim3(512),dim3(256),0,stream>>>(x,w1,b1,w2,b2,w3,b3,ws);
  k_finB   <<<dim3(1),  dim3(256),0,stream>>>(gm2,be2,ws);
  k_spatial<<<dim3(512),dim3(256),0,stream>>>(x,ws);
  k_mlp<1> <<<dim3(512),dim3(256),0,stream>>>(x,w1,b1,w2,b2,w3,b3,ws);
  k_finC   <<<dim3(1),  dim3(512),0,stream>>>(gm3,be3,ws);
  k_mlp<2> <<<dim3(512),dim3(256),0,stream>>>(x,w1,b1,w2,b2,w3,b3,ws);
  k_final  <<<dim3(16), dim3(256),0,stream>>>(wp,bp,gln,bln,out,ws);
}